// Round 5
// baseline (127.002 us; speedup 1.0000x reference)
//
#include <hip/hip_runtime.h>
#include <hip/hip_bf16.h>
#include <math.h>

using bf16 = __hip_bfloat16;
typedef __attribute__((ext_vector_type(8))) short short8;
typedef __attribute__((ext_vector_type(4))) float floatx4;
typedef __attribute__((ext_vector_type(4))) unsigned int uint4_;
typedef __attribute__((ext_vector_type(2))) unsigned int uint2_;

#define C_DIM   512
#define N_TOK   1024
#define NHEAD   8
#define HDIM    64
#define LN_EPSF 1e-5f

// RNE float -> bf16 bits (bit-hack; kept where values aren't pair-adjacent)
__device__ __forceinline__ unsigned short f2b(float f) {
    union { float f; unsigned int u; } v; v.f = f;
    unsigned int r = v.u + 0x7FFFu + ((v.u >> 16) & 1u);
    return (unsigned short)(r >> 16);
}
__device__ __forceinline__ float b2f(unsigned short u) {
    union { unsigned int i; float f; } v; v.i = ((unsigned int)u) << 16; return v.f;
}
// 2 floats -> packed bf16 pair in one VALU op (RNE, identical rounding to f2b)
__device__ __forceinline__ unsigned int cvt_pk_bf16(float lo, float hi) {
    unsigned int r;
    asm("v_cvt_pk_bf16_f32 %0, %1, %2" : "=v"(r) : "v"(lo), "v"(hi));
    return r;
}
// 2^x via the hardware transcendental, compiler-known (schedules/hazards handled)
__device__ __forceinline__ float fast_exp2(float x) {
    return __builtin_amdgcn_exp2f(x);
}
// async global->LDS, 16B per lane: dest = wave-uniform LDS base + lane*16,
// src = per-lane global address (guide m97/m104 semantics)
typedef __attribute__((address_space(3))) void lds_void;
typedef const __attribute__((address_space(1))) void gbl_void;
__device__ __forceinline__ void gl16(const void* g, void* l) {
    __builtin_amdgcn_global_load_lds((gbl_void*)g, (lds_void*)l, 16, 0, 0);
}

// ------ Kernel 1: fused LN(stats+normalize)+frag-transpose | sincos | w-conv ---------
__global__ __launch_bounds__(256) void lnx_kernel(
        const float* __restrict__ x, const float* __restrict__ w,
        const float* __restrict__ gamma, const float* __restrict__ beta,
        float* __restrict__ sc, unsigned short* __restrict__ wf,
        unsigned short* __restrict__ xnf) {
    __shared__ float xs[C_DIM][36];      // 73.7 KB; pad 36: 16B-aligned rows, spread banks
    __shared__ float red_s[8][32];
    __shared__ float red_q[8][32];
    __shared__ float muL[32], rsL[32];

    const int bx = blockIdx.x;
    const int t  = threadIdx.x;

    if (bx < 256) {
        const int b  = bx >> 5;              // batch
        const int n0 = (bx & 31) * 32;       // token strip
        const float* xb = x + (size_t)b * C_DIM * N_TOK;

        // P1: x strip -> LDS (float4 global reads, b128 LDS writes)
        #pragma unroll
        for (int i = 0; i < 16; ++i) {
            const int flat = i * 256 + t;    // [0,4096)
            const int c  = flat >> 3;
            const int f4 = flat & 7;
            const float4 v = *(const float4*)(xb + (size_t)c * N_TOK + n0 + f4 * 4);
            *(float4*)&xs[c][f4 * 4] = v;
        }
        __syncthreads();

        // P2: per-token mean/var (8 channel-chunks x 32 tokens; conflict-free reads)
        const int tl = t & 31, cg = t >> 5;
        float s = 0.f, q = 0.f;
        #pragma unroll 8
        for (int i2 = 0; i2 < 64; ++i2) {
            const float v = xs[cg * 64 + i2][tl];
            s += v; q += v * v;
        }
        red_s[cg][tl] = s; red_q[cg][tl] = q;
        __syncthreads();
        if (t < 32) {
            float S = 0.f, Q = 0.f;
            #pragma unroll
            for (int g2 = 0; g2 < 8; ++g2) { S += red_s[g2][t]; Q += red_q[g2][t]; }
            const float m   = S * (1.0f / C_DIM);
            const float var = Q * (1.0f / C_DIM) - m * m;
            muL[t] = m; rsL[t] = rsqrtf(var + LN_EPSF);
        }
        __syncthreads();

        // P3: normalize + frag-order write (token=lane&15, ch=kt*32+quad*8+j)
        const int wv   = t >> 6;
        const int lane = t & 63;
        const int cfr  = lane & 15;
        const int quad = lane >> 4;
        #pragma unroll
        for (int gg = 0; gg < 2; ++gg) {
            const int tloc = gg * 16 + cfr;
            const float m = muL[tloc], r = rsL[tloc];
            const int g16 = b * 64 + (n0 >> 4) + gg;
            #pragma unroll
            for (int kk = 0; kk < 4; ++kk) {
                const int kt  = wv * 4 + kk;
                const int ch0 = kt * 32 + quad * 8;
                const float4 g0 = *(const float4*)(gamma + ch0);
                const float4 g1 = *(const float4*)(gamma + ch0 + 4);
                const float4 b0 = *(const float4*)(beta + ch0);
                const float4 b1 = *(const float4*)(beta + ch0 + 4);
                float vv[8];
                #pragma unroll
                for (int j = 0; j < 8; ++j) vv[j] = (xs[ch0 + j][tloc] - m) * r;
                uint4_ pk;
                pk.x = cvt_pk_bf16(vv[0] * g0.x + b0.x, vv[1] * g0.y + b0.y);
                pk.y = cvt_pk_bf16(vv[2] * g0.z + b0.z, vv[3] * g0.w + b0.w);
                pk.z = cvt_pk_bf16(vv[4] * g1.x + b1.x, vv[5] * g1.y + b1.y);
                pk.w = cvt_pk_bf16(vv[6] * g1.z + b1.z, vv[7] * g1.w + b1.w);
                *(uint4_*)(xnf + (((size_t)g16 * 16 + kt) * 64 + lane) * 8) = pk;
            }
        }
    } else if (bx < 384) {
        const int idx = (bx - 256) * 256 + t;      // n*32 + f
        const int n = idx >> 5, f = idx & 31;
        const float fr = __expf((float)f * (-9.210340371976184f / 32.0f));
        float sv, cv;
        sincosf((float)n * fr, &sv, &cv);
        ((float2*)sc)[idx] = make_float2(sv, cv);
    } else {
        const int id   = (bx - 384) * 256 + t;     // chunk id in [0, 96*16*64)
        const int lane = id & 63;
        const int ksl  = (id >> 6) & 15;
        const int j16  = id >> 10;
        const int c    = lane & 15;
        const int quad = lane >> 4;
        const float* wp = w + (size_t)(j16 * 16 + c) * C_DIM + ksl * 32 + quad * 8;
        const float4 w0 = *(const float4*)(wp);
        const float4 w1 = *(const float4*)(wp + 4);
        uint4_ pk;
        pk.x = cvt_pk_bf16(w0.x, w0.y);
        pk.y = cvt_pk_bf16(w0.z, w0.w);
        pk.z = cvt_pk_bf16(w1.x, w1.y);
        pk.w = cvt_pk_bf16(w1.z, w1.w);
        *(uint4_*)(wf + (size_t)id * 8) = pk;
    }
}

// ---------------- Kernel 2: QKV MFMA GEMM + bias + RoPE + fragment-order scatter -------
__global__ __launch_bounds__(256) void qkv_mfma_kernel(
        const unsigned short* __restrict__ xnf, const unsigned short* __restrict__ wf,
        const float* __restrict__ bias, const float* __restrict__ sc,
        unsigned short* __restrict__ qfr, unsigned short* __restrict__ kfr,
        unsigned short* __restrict__ vfr) {
    __shared__ short Es[4][64][72];

    const int t    = threadIdx.x;
    const int wv   = t >> 6;
    const int lane = t & 63;
    const int cl   = lane & 15;
    const int quad = lane >> 4;
    const int t0   = blockIdx.x * 128 + (wv & 1) * 64;
    const int j0w  = blockIdx.y * 128 + (wv >> 1) * 64;
    const int which = j0w >> 9;                 // 0=q 1=k 2=v
    const int h     = (j0w >> 6) & 7;
    const int b     = t0 >> 10;
    const int n0q   = t0 & 1023;
    const int bh    = b * NHEAD + h;

    const unsigned short* ap = xnf + (size_t)(t0 >> 4) * 8192 + lane * 8;
    const unsigned short* bp = wf  + (size_t)(j0w >> 4) * 8192 + lane * 8;

    floatx4 acc[4][4];
    #pragma unroll
    for (int i = 0; i < 4; ++i)
        #pragma unroll
        for (int j = 0; j < 4; ++j) acc[i][j] = (floatx4){0.f, 0.f, 0.f, 0.f};

    #pragma unroll 2
    for (int kt = 0; kt < 16; ++kt) {
        short8 af[4], bfr[4];
        #pragma unroll
        for (int tt = 0; tt < 4; ++tt) af[tt]  = *(const short8*)(ap + ((size_t)tt * 16 + kt) * 512);
        #pragma unroll
        for (int jt = 0; jt < 4; ++jt) bfr[jt] = *(const short8*)(bp + ((size_t)jt * 16 + kt) * 512);
        __builtin_amdgcn_s_setprio(1);          // desync waves: T5 regime (m191)
        #pragma unroll
        for (int tt = 0; tt < 4; ++tt)
            #pragma unroll
            for (int jt = 0; jt < 4; ++jt)
                acc[tt][jt] = __builtin_amdgcn_mfma_f32_16x16x32_bf16(af[tt], bfr[jt], acc[tt][jt], 0, 0, 0);
        __builtin_amdgcn_s_setprio(0);
    }

    // fold q-scale (exact 2^-3) into the bias fmaf: Es holds pre-scaled S for q-waves
    const float os = (which == 0) ? 0.125f : 1.0f;
    float bj[4];
    #pragma unroll
    for (int jt = 0; jt < 4; ++jt) bj[jt] = bias[j0w + jt * 16 + cl] * os;
    #pragma unroll
    for (int tt = 0; tt < 4; ++tt)
        #pragma unroll
        for (int jt = 0; jt < 4; ++jt)
            #pragma unroll
            for (int r = 0; r < 4; ++r)
                Es[wv][tt * 16 + quad * 4 + r][jt * 16 + cl] = (short)f2b(fmaf(acc[tt][jt][r], os, bj[jt]));
    // same-wave LDS read-after-write: ordered by lgkmcnt (no barrier needed)

    if (which == 2) {
        unsigned short* vfb = vfr + ((size_t)bh * 16 + (n0q >> 6)) * 4096;
        #pragma unroll
        for (int dt = 0; dt < 4; ++dt) {
            #pragma unroll
            for (int ks = 0; ks < 2; ++ks) {
                short8 pk;
                #pragma unroll
                for (int j = 0; j < 8; ++j)
                    pk[j] = Es[wv][ks * 32 + quad * 8 + j][dt * 16 + cl];
                *(short8*)(vfb + (((size_t)dt * 2 + ks) * 64 + lane) * 8) = pk;
            }
        }
    } else {
        unsigned short* base = (which == 0)
            ? qfr + ((size_t)bh * 64 + (n0q >> 4)) * 1024
            : kfr + ((size_t)bh * 16 + (n0q >> 6)) * 4096;
        #pragma unroll
        for (int mt = 0; mt < 4; ++mt) {
            const int n = n0q + mt * 16 + cl;
            const float* scp = sc + ((size_t)n * 32 + quad * 4) * 2;
            #pragma unroll
            for (int ks = 0; ks < 2; ++ks) {
                const short8 v8 = *(const short8*)&Es[wv][mt * 16 + cl][ks * 32 + quad * 8];
                const short8 p8 = *(const short8*)&Es[wv][mt * 16 + cl][(ks ^ 1) * 32 + quad * 8];
                const float* sp = scp + ks * 32;               // f = ks*16 + quad*4
                const float4 s0 = *(const float4*)sp;
                const float4 s1 = *(const float4*)(sp + 4);
                const float sv[4] = {s0.x, s0.z, s1.x, s1.z};
                const float cv[4] = {s0.y, s0.w, s1.y, s1.w};
                const float sgn = ks ? 1.0f : -1.0f;           // d<32 <=> ks==0
                uint4_ pk;
                unsigned int pw[4];
                #pragma unroll
                for (int f = 0; f < 4; ++f) {
                    const float svs = sgn * sv[f];
                    const float a0 = b2f((unsigned short)v8[2 * f]);
                    const float a1 = b2f((unsigned short)v8[2 * f + 1]);
                    const float p0 = b2f((unsigned short)p8[2 * f]);
                    const float p1 = b2f((unsigned short)p8[2 * f + 1]);
                    pw[f] = cvt_pk_bf16(fmaf(p0, svs, a0 * cv[f]),
                                        fmaf(p1, svs, a1 * cv[f]));
                }
                pk.x = pw[0]; pk.y = pw[1]; pk.z = pw[2]; pk.w = pw[3];
                *(uint4_*)(base + (((size_t)mt * 2 + ks) * 64 + lane) * 8) = pk;
            }
        }
    }
}

// ------- Kernel 3: MFMA flash attention, block-shared async-LDS K/V -----------------
// Diagnosis: direct-from-L2 K/V was L2-BW-bound (16 KB/wave/kt, 512 MB total; ~2300
// cyc/kt vs ~320 cyc MFMA). Fix: stage each kt's 16 KB K+V chunk ONCE per block into
// double-buffered LDS via global_load_lds (16 B), ISSUED at the top of kt so the
// __syncthreads drain at the bottom is free (T14 issue-early). 4x less L2 traffic.
// Softmax/PV math unchanged from R3 (exp2-domain, cvt_pk, setprio).
__global__ __launch_bounds__(256, 2) void attn_mfma_kernel(
        const unsigned short* __restrict__ qfr, const unsigned short* __restrict__ kfr,
        const unsigned short* __restrict__ vfr, float* __restrict__ out) {
    __shared__ __align__(16) short kbuf[2][4096];        // 16 KB: dbuf K frag chunks
    __shared__ __align__(16) short vbuf[2][4096];        // 16 KB: dbuf V frag chunks
    __shared__ __align__(16) short Plds[4][2][16][72];   // per-wave P strips (18.4 KB)

    const int t    = threadIdx.x;
    const int wv   = t >> 6;
    const int lane = t & 63;
    const int c    = lane & 15;
    const int quad = lane >> 4;
    const int i    = blockIdx.x;                   // [0,512)
    const int bh   = (i & 7) * 8 + ((i >> 3) & 7); // XCD swizzle: 8 bh per XCD
    const int q32  = (i >> 6) * 4 + wv;            // wave's 32-q tile, [0,32)
    const int b    = bh >> 3, h = bh & 7;

    const unsigned short* qp   = qfr + ((size_t)bh * 64 + q32 * 2) * 1024 + lane * 8;
    const unsigned short* kraw = kfr + (size_t)bh * 65536;   // no lane offset: staging
    const unsigned short* vraw = vfr + (size_t)bh * 65536;

    short8 qf[2][2];
    qf[0][0] = *(const short8*)(qp);
    qf[0][1] = *(const short8*)(qp + 512);
    qf[1][0] = *(const short8*)(qp + 1024);
    qf[1][1] = *(const short8*)(qp + 1536);

    floatx4 o_acc[4][2];
    float l_acc[2] = {0.f, 0.f};
    #pragma unroll
    for (int dt = 0; dt < 4; ++dt) {
        o_acc[dt][0] = (floatx4){0.f, 0.f, 0.f, 0.f};
        o_acc[dt][1] = (floatx4){0.f, 0.f, 0.f, 0.f};
    }

    const float LOG2E  = 1.4426950408889634f;
    const float ESHIFT = -23.083120654223414f;     // -16*log2(e): exp(s-16)=2^(s*log2e+ESHIFT)

    // stage kt's 16 KB chunk: wave wv covers K segs {2wv,2wv+1} and V segs {2wv,2wv+1}
    auto stage = [&](int kt, int cur) {
        const unsigned short* kc = kraw + (size_t)kt * 4096;
        const unsigned short* vc = vraw + (size_t)kt * 4096;
        #pragma unroll
        for (int s2 = 0; s2 < 2; ++s2) {
            const int seg = wv * 2 + s2;
            gl16(kc + seg * 512 + lane * 8, &kbuf[cur][seg * 512]);
            gl16(vc + seg * 512 + lane * 8, &vbuf[cur][seg * 512]);
        }
    };

    auto step = [&](int cur) {
        // S^T: rows = keys (mt tile), cols = q (c); one 16x16 tile per (mt, u)
        floatx4 st[4][2];
        #pragma unroll
        for (int mt = 0; mt < 4; ++mt) {
            const short8 k0 = *(const short8*)&kbuf[cur][((mt * 2 + 0) * 64 + lane) * 8];
            const short8 k1 = *(const short8*)&kbuf[cur][((mt * 2 + 1) * 64 + lane) * 8];
            __builtin_amdgcn_s_setprio(1);
            #pragma unroll
            for (int u = 0; u < 2; ++u) {
                floatx4 z = (floatx4){0.f, 0.f, 0.f, 0.f};
                z = __builtin_amdgcn_mfma_f32_16x16x32_bf16(k0, qf[u][0], z, 0, 0, 0);
                st[mt][u] = __builtin_amdgcn_mfma_f32_16x16x32_bf16(k1, qf[u][1], z, 0, 0, 0);
            }
            __builtin_amdgcn_s_setprio(0);
        }

        // fixed-shift softmax in exp2 domain; pack pairs with v_cvt_pk_bf16_f32
        #pragma unroll
        for (int u = 0; u < 2; ++u)
            #pragma unroll
            for (int mt = 0; mt < 4; ++mt) {
                const float e0 = fast_exp2(fmaf(st[mt][u][0], LOG2E, ESHIFT));
                const float e1 = fast_exp2(fmaf(st[mt][u][1], LOG2E, ESHIFT));
                const float e2 = fast_exp2(fmaf(st[mt][u][2], LOG2E, ESHIFT));
                const float e3 = fast_exp2(fmaf(st[mt][u][3], LOG2E, ESHIFT));
                l_acc[u] += (e0 + e1) + (e2 + e3);
                uint2_ pk;
                pk.x = cvt_pk_bf16(e0, e1);
                pk.y = cvt_pk_bf16(e2, e3);
                *(uint2_*)&Plds[wv][u][c][mt * 16 + quad * 4] = pk;
            }

        // PV: O^T += V^T . P^T  (P round-trip is same-wave, lgkmcnt-ordered)
        #pragma unroll
        for (int u = 0; u < 2; ++u) {
            const short8 pf0 = *(const short8*)&Plds[wv][u][c][quad * 8];
            const short8 pf1 = *(const short8*)&Plds[wv][u][c][32 + quad * 8];
            __builtin_amdgcn_s_setprio(1);
            #pragma unroll
            for (int dt = 0; dt < 4; ++dt) {
                const short8 v0 = *(const short8*)&vbuf[cur][((dt * 2 + 0) * 64 + lane) * 8];
                const short8 v1 = *(const short8*)&vbuf[cur][((dt * 2 + 1) * 64 + lane) * 8];
                o_acc[dt][u] = __builtin_amdgcn_mfma_f32_16x16x32_bf16(v0, pf0, o_acc[dt][u], 0, 0, 0);
                o_acc[dt][u] = __builtin_amdgcn_mfma_f32_16x16x32_bf16(v1, pf1, o_acc[dt][u], 0, 0, 0);
            }
            __builtin_amdgcn_s_setprio(0);
        }
    };

    stage(0, 0);
    __syncthreads();                       // prologue loads landed (vmcnt drain)
    #pragma unroll 1
    for (int kt = 0; kt < 16; ++kt) {
        const int cur = kt & 1;
        if (kt < 15) stage(kt + 1, cur ^ 1);   // in flight across the whole compute
        step(cur);
        __syncthreads();                   // drain (free: loads issued ~600cyc ago) + join
    }

    #pragma unroll
    for (int u = 0; u < 2; ++u) {
        float l = l_acc[u];
        l += __shfl_xor(l, 16);
        l += __shfl_xor(l, 32);
        const float inv = 1.0f / l;
        const int qcol = (q32 * 2 + u) * 16 + c;
        #pragma unroll
        for (int dt = 0; dt < 4; ++dt)
            #pragma unroll
            for (int r = 0; r < 4; ++r) {
                const int d = dt * 16 + quad * 4 + r;
                out[((size_t)b * C_DIM + h * HDIM + d) * N_TOK + qcol] = o_acc[dt][u][r] * inv;
            }
    }
}

extern "C" void kernel_launch(void* const* d_in, const int* in_sizes, int n_in,
                              void* d_out, int out_size, void* d_ws, size_t ws_size,
                              hipStream_t stream) {
    const float* x     = (const float*)d_in[0];
    const float* w     = (const float*)d_in[1];
    const float* bias  = (const float*)d_in[2];
    const float* gamma = (const float*)d_in[3];
    const float* beta  = (const float*)d_in[4];
    float* out = (float*)d_out;

    char* ws = (char*)d_ws;
    unsigned short* qfr = (unsigned short*)(ws + 65536);        // 8 MB
    unsigned short* kfr = (unsigned short*)(ws + 65536 + 8388608);
    unsigned short* vfr = (unsigned short*)(ws + 65536 + 16777216);
    unsigned short* xnf = (unsigned short*)(ws + 65536 + 25165824);  // 8 MB
    unsigned short* wf  = (unsigned short*)(ws + 65536 + 33554432);  // 1.5 MB
    float* sc           = (float*)(ws + 65536 + 35127296);           // 256 KB

    hipLaunchKernelGGL(lnx_kernel, dim3(768), dim3(256), 0, stream,
                       x, w, gamma, beta, sc, wf, xnf);
    hipLaunchKernelGGL(qkv_mfma_kernel, dim3(64, 12), dim3(256), 0, stream,
                       xnf, wf, bias, sc, qfr, kfr, vfr);
    hipLaunchKernelGGL(attn_mfma_kernel, dim3(512), dim3(256), 0, stream, qfr, kfr, vfr, out);
}

// Round 6
// 125.952 us; speedup vs baseline: 1.0083x; 1.0083x over previous
//
#include <hip/hip_runtime.h>
#include <hip/hip_bf16.h>
#include <math.h>

using bf16 = __hip_bfloat16;
typedef __attribute__((ext_vector_type(8))) short short8;
typedef __attribute__((ext_vector_type(4))) float floatx4;
typedef __attribute__((ext_vector_type(4))) unsigned int uint4_;
typedef __attribute__((ext_vector_type(2))) unsigned int uint2_;

#define C_DIM   512
#define N_TOK   1024
#define NHEAD   8
#define HDIM    64
#define LN_EPSF 1e-5f

// RNE float -> bf16 bits (bit-hack; kept where values aren't pair-adjacent)
__device__ __forceinline__ unsigned short f2b(float f) {
    union { float f; unsigned int u; } v; v.f = f;
    unsigned int r = v.u + 0x7FFFu + ((v.u >> 16) & 1u);
    return (unsigned short)(r >> 16);
}
__device__ __forceinline__ float b2f(unsigned short u) {
    union { unsigned int i; float f; } v; v.i = ((unsigned int)u) << 16; return v.f;
}
// 2 floats -> packed bf16 pair in one VALU op (RNE, identical rounding to f2b)
__device__ __forceinline__ unsigned int cvt_pk_bf16(float lo, float hi) {
    unsigned int r;
    asm("v_cvt_pk_bf16_f32 %0, %1, %2" : "=v"(r) : "v"(lo), "v"(hi));
    return r;
}
// 2^x via the hardware transcendental, compiler-known (schedules/hazards handled)
__device__ __forceinline__ float fast_exp2(float x) {
    return __builtin_amdgcn_exp2f(x);
}
// async global->LDS, 16B per lane: dest = wave-uniform LDS base (+lane*16 by HW),
// src = per-lane global address (guide m97/m104 semantics)
typedef __attribute__((address_space(3))) void lds_void;
typedef const __attribute__((address_space(1))) void gbl_void;
__device__ __forceinline__ void gl16(const void* g, void* l) {
    __builtin_amdgcn_global_load_lds((gbl_void*)g, (lds_void*)l, 16, 0, 0);
}

// ------ Kernel 1: fused LN(stats-in-registers + normalize)+frag-transpose | sincos | w-conv
__global__ __launch_bounds__(256) void lnx_kernel(
        const float* __restrict__ x, const float* __restrict__ w,
        const float* __restrict__ gamma, const float* __restrict__ beta,
        float* __restrict__ sc, unsigned short* __restrict__ wf,
        unsigned short* __restrict__ xnf) {
    __shared__ float xs[C_DIM][36];      // 73.7 KB; pad 36: 16B-aligned rows, spread banks
    __shared__ float redw_s[4][8][4];
    __shared__ float redw_q[4][8][4];
    __shared__ float muL[32], rsL[32];

    const int bx = blockIdx.x;
    const int t  = threadIdx.x;

    if (bx < 256) {
        const int b  = bx >> 5;              // batch
        const int n0 = (bx & 31) * 32;       // token strip
        const float* xb = x + (size_t)b * C_DIM * N_TOK;

        // P1: x strip -> LDS, accumulating this thread's 4-token partial stats in regs
        float s4[4] = {0.f, 0.f, 0.f, 0.f}, q4[4] = {0.f, 0.f, 0.f, 0.f};
        #pragma unroll
        for (int i = 0; i < 16; ++i) {
            const int flat = i * 256 + t;    // [0,4096)
            const int c  = flat >> 3;        // = i*32 + (t>>3): 16 channels/thread
            const int f4 = flat & 7;         // fixed token group = t&7
            const float4 v = *(const float4*)(xb + (size_t)c * N_TOK + n0 + f4 * 4);
            *(float4*)&xs[c][f4 * 4] = v;
            s4[0] += v.x; q4[0] += v.x * v.x;
            s4[1] += v.y; q4[1] += v.y * v.y;
            s4[2] += v.z; q4[2] += v.z * v.z;
            s4[3] += v.w; q4[3] += v.w * v.w;
        }
        // butterfly over lanes sharing the token group (bits 3..5 of lane)
        #pragma unroll
        for (int m = 8; m <= 32; m <<= 1)
            #pragma unroll
            for (int j = 0; j < 4; ++j) {
                s4[j] += __shfl_xor(s4[j], m);
                q4[j] += __shfl_xor(q4[j], m);
            }
        const int wv = t >> 6, lane = t & 63;
        if (lane < 8) {
            #pragma unroll
            for (int j = 0; j < 4; ++j) {
                redw_s[wv][lane][j] = s4[j];
                redw_q[wv][lane][j] = q4[j];
            }
        }
        __syncthreads();
        if (t < 32) {
            float S = 0.f, Q = 0.f;
            #pragma unroll
            for (int w2 = 0; w2 < 4; ++w2) {
                S += redw_s[w2][t >> 2][t & 3];
                Q += redw_q[w2][t >> 2][t & 3];
            }
            const float m   = S * (1.0f / C_DIM);
            const float var = Q * (1.0f / C_DIM) - m * m;
            muL[t] = m; rsL[t] = rsqrtf(var + LN_EPSF);
        }
        __syncthreads();

        // P3: normalize + frag-order write (token=lane&15, ch=kt*32+quad*8+j)
        const int cfr  = lane & 15;
        const int quad = lane >> 4;
        #pragma unroll
        for (int gg = 0; gg < 2; ++gg) {
            const int tloc = gg * 16 + cfr;
            const float m = muL[tloc], r = rsL[tloc];
            const int g16 = b * 64 + (n0 >> 4) + gg;
            #pragma unroll
            for (int kk = 0; kk < 4; ++kk) {
                const int kt  = wv * 4 + kk;
                const int ch0 = kt * 32 + quad * 8;
                const float4 g0 = *(const float4*)(gamma + ch0);
                const float4 g1 = *(const float4*)(gamma + ch0 + 4);
                const float4 b0 = *(const float4*)(beta + ch0);
                const float4 b1 = *(const float4*)(beta + ch0 + 4);
                float vv[8];
                #pragma unroll
                for (int j = 0; j < 8; ++j) vv[j] = (xs[ch0 + j][tloc] - m) * r;
                uint4_ pk;
                pk.x = cvt_pk_bf16(vv[0] * g0.x + b0.x, vv[1] * g0.y + b0.y);
                pk.y = cvt_pk_bf16(vv[2] * g0.z + b0.z, vv[3] * g0.w + b0.w);
                pk.z = cvt_pk_bf16(vv[4] * g1.x + b1.x, vv[5] * g1.y + b1.y);
                pk.w = cvt_pk_bf16(vv[6] * g1.z + b1.z, vv[7] * g1.w + b1.w);
                *(uint4_*)(xnf + (((size_t)g16 * 16 + kt) * 64 + lane) * 8) = pk;
            }
        }
    } else if (bx < 384) {
        const int idx = (bx - 256) * 256 + t;      // n*32 + f
        const int n = idx >> 5, f = idx & 31;
        const float fr = __expf((float)f * (-9.210340371976184f / 32.0f));
        float sv, cv;
        sincosf((float)n * fr, &sv, &cv);
        ((float2*)sc)[idx] = make_float2(sv, cv);
    } else {
        const int id   = (bx - 384) * 256 + t;     // chunk id in [0, 96*16*64)
        const int lane = id & 63;
        const int ksl  = (id >> 6) & 15;
        const int j16  = id >> 10;
        const int c    = lane & 15;
        const int quad = lane >> 4;
        const float* wp = w + (size_t)(j16 * 16 + c) * C_DIM + ksl * 32 + quad * 8;
        const float4 w0 = *(const float4*)(wp);
        const float4 w1 = *(const float4*)(wp + 4);
        uint4_ pk;
        pk.x = cvt_pk_bf16(w0.x, w0.y);
        pk.y = cvt_pk_bf16(w0.z, w0.w);
        pk.z = cvt_pk_bf16(w1.x, w1.y);
        pk.w = cvt_pk_bf16(w1.z, w1.w);
        *(uint4_*)(wf + (size_t)id * 8) = pk;
    }
}

// ---------------- Kernel 2: QKV MFMA GEMM, gl16-staged panels + bias + RoPE ----------
// qkv's 4 waves had only 2-way fragment sharing; 3 blocks/CU x 16 KB/kt thrashed the
// 32 KB L1 and every load round-tripped VGPRs. Now: block stages its unique 16 KB
// (8 A-tiles + 8 B-tiles) per kt via global_load_lds into a double buffer (issued
// one kt ahead), waves read frags from LDS. Staging buffer is UNIONED with Es (Es is
// dead until after the K-loop) -> no LDS growth, occupancy stays 3 blocks/CU.
__global__ __launch_bounds__(256) void qkv_mfma_kernel(
        const unsigned short* __restrict__ xnf, const unsigned short* __restrict__ wf,
        const float* __restrict__ bias, const float* __restrict__ sc,
        unsigned short* __restrict__ qfr, unsigned short* __restrict__ kfr,
        unsigned short* __restrict__ vfr) {
    __shared__ __align__(16) char smem[36864];   // max(staging 32 KB, Es 36.9 KB)
    short* stg = (short*)smem;                   // [2][8192] shorts while K-loop runs
    short (*Es)[72] = (short(*)[72])smem;        // [4*64][72] after the K-loop

    const int t    = threadIdx.x;
    const int wv   = t >> 6;
    const int lane = t & 63;
    const int cl   = lane & 15;
    const int quad = lane >> 4;
    const int tb   = blockIdx.x * 128;
    const int jb   = blockIdx.y * 128;
    const int t0   = tb + (wv & 1) * 64;
    const int j0w  = jb + (wv >> 1) * 64;
    const int which = j0w >> 9;                 // 0=q 1=k 2=v
    const int h     = (j0w >> 6) & 7;
    const int b     = t0 >> 10;
    const int n0q   = t0 & 1023;
    const int bh    = b * NHEAD + h;
    const int g16b  = tb >> 4;                  // block's 8 A-tiles
    const int j16b  = jb >> 4;                  // block's 8 B-tiles

    // stage kt's 16 tiles (1 KB each); wave wv covers tile-ids [4wv, 4wv+4)
    auto stage = [&](int kt, int cur) {
        short* dst = stg + cur * 8192;
        #pragma unroll
        for (int s = 0; s < 4; ++s) {
            const int id = wv * 4 + s;
            const unsigned short* src = (id < 8)
                ? xnf + (size_t)(g16b + id) * 8192 + kt * 512 + lane * 8
                : wf  + (size_t)(j16b + (id - 8)) * 8192 + kt * 512 + lane * 8;
            gl16(src, dst + id * 512);
        }
    };

    floatx4 acc[4][4];
    #pragma unroll
    for (int i = 0; i < 4; ++i)
        #pragma unroll
        for (int j = 0; j < 4; ++j) acc[i][j] = (floatx4){0.f, 0.f, 0.f, 0.f};

    stage(0, 0);
    #pragma unroll 1
    for (int kt = 0; kt < 16; ++kt) {
        const int cur = kt & 1;
        __syncthreads();                 // stage(kt) landed; buf[cur] free of old readers
        if (kt < 15) stage(kt + 1, cur ^ 1);   // in flight across this kt's compute
        const short* base = stg + cur * 8192;
        short8 af[4], bfr[4];
        #pragma unroll
        for (int tt = 0; tt < 4; ++tt)
            af[tt]  = *(const short8*)(base + ((wv & 1) * 4 + tt) * 512 + lane * 8);
        #pragma unroll
        for (int jt = 0; jt < 4; ++jt)
            bfr[jt] = *(const short8*)(base + (8 + (wv >> 1) * 4 + jt) * 512 + lane * 8);
        __builtin_amdgcn_s_setprio(1);
        #pragma unroll
        for (int tt = 0; tt < 4; ++tt)
            #pragma unroll
            for (int jt = 0; jt < 4; ++jt)
                acc[tt][jt] = __builtin_amdgcn_mfma_f32_16x16x32_bf16(af[tt], bfr[jt], acc[tt][jt], 0, 0, 0);
        __builtin_amdgcn_s_setprio(0);
    }
    __syncthreads();   // all waves done reading staging before Es overlays it

    // fold q-scale (exact 2^-3) into the bias fmaf: Es holds pre-scaled S for q-waves
    const float os = (which == 0) ? 0.125f : 1.0f;
    float bj[4];
    #pragma unroll
    for (int jt = 0; jt < 4; ++jt) bj[jt] = bias[j0w + jt * 16 + cl] * os;
    #pragma unroll
    for (int tt = 0; tt < 4; ++tt)
        #pragma unroll
        for (int jt = 0; jt < 4; ++jt)
            #pragma unroll
            for (int r = 0; r < 4; ++r)
                Es[wv * 64 + tt * 16 + quad * 4 + r][jt * 16 + cl] = (short)f2b(fmaf(acc[tt][jt][r], os, bj[jt]));
    // same-wave LDS read-after-write below: ordered by lgkmcnt (no barrier needed)

    if (which == 2) {
        unsigned short* vfb = vfr + ((size_t)bh * 16 + (n0q >> 6)) * 4096;
        #pragma unroll
        for (int dt = 0; dt < 4; ++dt) {
            #pragma unroll
            for (int ks = 0; ks < 2; ++ks) {
                short8 pk;
                #pragma unroll
                for (int j = 0; j < 8; ++j)
                    pk[j] = Es[wv * 64 + ks * 32 + quad * 8 + j][dt * 16 + cl];
                *(short8*)(vfb + (((size_t)dt * 2 + ks) * 64 + lane) * 8) = pk;
            }
        }
    } else {
        unsigned short* base = (which == 0)
            ? qfr + ((size_t)bh * 64 + (n0q >> 4)) * 1024
            : kfr + ((size_t)bh * 16 + (n0q >> 6)) * 4096;
        #pragma unroll
        for (int mt = 0; mt < 4; ++mt) {
            const int n = n0q + mt * 16 + cl;
            const float* scp = sc + ((size_t)n * 32 + quad * 4) * 2;
            #pragma unroll
            for (int ks = 0; ks < 2; ++ks) {
                const short8 v8 = *(const short8*)&Es[wv * 64 + mt * 16 + cl][ks * 32 + quad * 8];
                const short8 p8 = *(const short8*)&Es[wv * 64 + mt * 16 + cl][(ks ^ 1) * 32 + quad * 8];
                const float* sp = scp + ks * 32;               // f = ks*16 + quad*4
                const float4 s0 = *(const float4*)sp;
                const float4 s1 = *(const float4*)(sp + 4);
                const float sv[4] = {s0.x, s0.z, s1.x, s1.z};
                const float cv[4] = {s0.y, s0.w, s1.y, s1.w};
                const float sgn = ks ? 1.0f : -1.0f;           // d<32 <=> ks==0
                uint4_ pk;
                unsigned int pw[4];
                #pragma unroll
                for (int f = 0; f < 4; ++f) {
                    const float svs = sgn * sv[f];
                    const float a0 = b2f((unsigned short)v8[2 * f]);
                    const float a1 = b2f((unsigned short)v8[2 * f + 1]);
                    const float p0 = b2f((unsigned short)p8[2 * f]);
                    const float p1 = b2f((unsigned short)p8[2 * f + 1]);
                    pw[f] = cvt_pk_bf16(fmaf(p0, svs, a0 * cv[f]),
                                        fmaf(p1, svs, a1 * cv[f]));
                }
                pk.x = pw[0]; pk.y = pw[1]; pk.z = pw[2]; pk.w = pw[3];
                *(uint4_*)(base + (((size_t)mt * 2 + ks) * 64 + lane) * 8) = pk;
            }
        }
    }
}

// ------- Kernel 3: MFMA flash attention, barrier-free, K/V direct from L1/L2 --------
// Reverted to the best-measured R4 form: all 4 waves load the identical 16 KB chunk
// per kt, which the per-CU L1 dedupes (R5's LDS staging proved neutral). exp2-domain
// softmax, cvt_pk P-pack, setprio around MFMA clusters.
__global__ __launch_bounds__(256, 2) void attn_mfma_kernel(
        const unsigned short* __restrict__ qfr, const unsigned short* __restrict__ kfr,
        const unsigned short* __restrict__ vfr, float* __restrict__ out) {
    __shared__ __align__(16) short Plds[4][2][16][72];   // per-wave, per-u P strip (18 KB)

    const int t    = threadIdx.x;
    const int wv   = t >> 6;
    const int lane = t & 63;
    const int c    = lane & 15;
    const int quad = lane >> 4;
    const int i    = blockIdx.x;                   // [0,512)
    const int bh   = (i & 7) * 8 + ((i >> 3) & 7); // XCD swizzle: 8 bh per XCD
    const int q32  = (i >> 6) * 4 + wv;            // wave's 32-q tile, [0,32)
    const int b    = bh >> 3, h = bh & 7;

    const unsigned short* qp   = qfr + ((size_t)bh * 64 + q32 * 2) * 1024 + lane * 8;
    const unsigned short* kraw = kfr + (size_t)bh * 65536 + lane * 8;
    const unsigned short* vraw = vfr + (size_t)bh * 65536 + lane * 8;

    short8 qf[2][2];
    qf[0][0] = *(const short8*)(qp);
    qf[0][1] = *(const short8*)(qp + 512);
    qf[1][0] = *(const short8*)(qp + 1024);
    qf[1][1] = *(const short8*)(qp + 1536);

    floatx4 o_acc[4][2];
    float l_acc[2] = {0.f, 0.f};
    #pragma unroll
    for (int dt = 0; dt < 4; ++dt) {
        o_acc[dt][0] = (floatx4){0.f, 0.f, 0.f, 0.f};
        o_acc[dt][1] = (floatx4){0.f, 0.f, 0.f, 0.f};
    }

    const float LOG2E  = 1.4426950408889634f;
    const float ESHIFT = -23.083120654223414f;     // -16*log2(e): exp(s-16)=2^(s*log2e+ESHIFT)

    short8 kfA[4][2], vfA[4][2], kfB[4][2], vfB[4][2];

    auto loadf = [&](short8 (&kf)[4][2], short8 (&vf)[4][2], int kt) {
        const unsigned short* kc = kraw + (size_t)kt * 4096;
        const unsigned short* vc = vraw + (size_t)kt * 4096;
        #pragma unroll
        for (int mt = 0; mt < 4; ++mt)
            #pragma unroll
            for (int ks = 0; ks < 2; ++ks) {
                kf[mt][ks] = *(const short8*)(kc + (mt * 2 + ks) * 512);
                vf[mt][ks] = *(const short8*)(vc + (mt * 2 + ks) * 512);
            }
    };

    auto step = [&](short8 (&kf)[4][2], short8 (&vf)[4][2]) {
        // S^T: rows = keys (mt tile), cols = q (c); one 16x16 tile per (mt, u)
        floatx4 st[4][2];
        __builtin_amdgcn_s_setprio(1);
        #pragma unroll
        for (int mt = 0; mt < 4; ++mt)
            #pragma unroll
            for (int u = 0; u < 2; ++u) {
                floatx4 z = (floatx4){0.f, 0.f, 0.f, 0.f};
                z = __builtin_amdgcn_mfma_f32_16x16x32_bf16(kf[mt][0], qf[u][0], z, 0, 0, 0);
                st[mt][u] = __builtin_amdgcn_mfma_f32_16x16x32_bf16(kf[mt][1], qf[u][1], z, 0, 0, 0);
            }
        __builtin_amdgcn_s_setprio(0);

        // fixed-shift softmax in exp2 domain; pack pairs with v_cvt_pk_bf16_f32
        #pragma unroll
        for (int u = 0; u < 2; ++u)
            #pragma unroll
            for (int mt = 0; mt < 4; ++mt) {
                const float e0 = fast_exp2(fmaf(st[mt][u][0], LOG2E, ESHIFT));
                const float e1 = fast_exp2(fmaf(st[mt][u][1], LOG2E, ESHIFT));
                const float e2 = fast_exp2(fmaf(st[mt][u][2], LOG2E, ESHIFT));
                const float e3 = fast_exp2(fmaf(st[mt][u][3], LOG2E, ESHIFT));
                l_acc[u] += (e0 + e1) + (e2 + e3);
                uint2_ pk;
                pk.x = cvt_pk_bf16(e0, e1);
                pk.y = cvt_pk_bf16(e2, e3);
                *(uint2_*)&Plds[wv][u][c][mt * 16 + quad * 4] = pk;
            }

        // PV: O^T += V^T . P^T  (P round-trip is same-wave, lgkmcnt-ordered)
        #pragma unroll
        for (int u = 0; u < 2; ++u) {
            const short8 pf0 = *(const short8*)&Plds[wv][u][c][quad * 8];
            const short8 pf1 = *(const short8*)&Plds[wv][u][c][32 + quad * 8];
            __builtin_amdgcn_s_setprio(1);
            #pragma unroll
            for (int dt = 0; dt < 4; ++dt) {
                o_acc[dt][u] = __builtin_amdgcn_mfma_f32_16x16x32_bf16(vf[dt][0], pf0, o_acc[dt][u], 0, 0, 0);
                o_acc[dt][u] = __builtin_amdgcn_mfma_f32_16x16x32_bf16(vf[dt][1], pf1, o_acc[dt][u], 0, 0, 0);
            }
            __builtin_amdgcn_s_setprio(0);
        }
    };

    loadf(kfA, vfA, 0);
    #pragma unroll 1
    for (int kt = 0; kt < 16; kt += 2) {
        loadf(kfB, vfB, kt + 1);          // in flight across step A (no barrier drain)
        step(kfA, vfA);
        if (kt + 2 < 16) loadf(kfA, vfA, kt + 2);
        step(kfB, vfB);
    }

    #pragma unroll
    for (int u = 0; u < 2; ++u) {
        float l = l_acc[u];
        l += __shfl_xor(l, 16);
        l += __shfl_xor(l, 32);
        const float inv = 1.0f / l;
        const int qcol = (q32 * 2 + u) * 16 + c;
        #pragma unroll
        for (int dt = 0; dt < 4; ++dt)
            #pragma unroll
            for (int r = 0; r < 4; ++r) {
                const int d = dt * 16 + quad * 4 + r;
                out[((size_t)b * C_DIM + h * HDIM + d) * N_TOK + qcol] = o_acc[dt][u][r] * inv;
            }
    }
}

extern "C" void kernel_launch(void* const* d_in, const int* in_sizes, int n_in,
                              void* d_out, int out_size, void* d_ws, size_t ws_size,
                              hipStream_t stream) {
    const float* x     = (const float*)d_in[0];
    const float* w     = (const float*)d_in[1];
    const float* bias  = (const float*)d_in[2];
    const float* gamma = (const float*)d_in[3];
    const float* beta  = (const float*)d_in[4];
    float* out = (float*)d_out;

    char* ws = (char*)d_ws;
    unsigned short* qfr = (unsigned short*)(ws + 65536);        // 8 MB
    unsigned short* kfr = (unsigned short*)(ws + 65536 + 8388608);
    unsigned short* vfr = (unsigned short*)(ws + 65536 + 16777216);
    unsigned short* xnf = (unsigned short*)(ws + 65536 + 25165824);  // 8 MB
    unsigned short* wf  = (unsigned short*)(ws + 65536 + 33554432);  // 1.5 MB
    float* sc           = (float*)(ws + 65536 + 35127296);           // 256 KB

    hipLaunchKernelGGL(lnx_kernel, dim3(768), dim3(256), 0, stream,
                       x, w, gamma, beta, sc, wf, xnf);
    hipLaunchKernelGGL(qkv_mfma_kernel, dim3(64, 12), dim3(256), 0, stream,
                       xnf, wf, bias, sc, qfr, kfr, vfr);
    hipLaunchKernelGGL(attn_mfma_kernel, dim3(512), dim3(256), 0, stream, qfr, kfr, vfr, out);
}